// Round 3
// baseline (234.086 us; speedup 1.0000x reference)
//
#include <hip/hip_runtime.h>

typedef __attribute__((ext_vector_type(8))) short short8;
typedef __attribute__((ext_vector_type(4))) float f32x4;

#define GLDS16(gp, lp)                                                                     \
  __builtin_amdgcn_global_load_lds(                                                        \
      (const __attribute__((address_space(1))) unsigned int*)(gp),                         \
      (__attribute__((address_space(3))) unsigned int*)(lp), 16, 0, 0)

__device__ __forceinline__ unsigned short f2bf(float f) {
  unsigned u = __float_as_uint(f);
  u += 0x7FFFu + ((u >> 16) & 1u);
  return (unsigned short)(u >> 16);
}
__device__ __forceinline__ float bf2f(unsigned short h) {
  return __uint_as_float(((unsigned)h) << 16);
}
__device__ __forceinline__ unsigned cvt_pk_bf16(float a, float b) {
  unsigned r;
  asm("v_cvt_pk_bf16_f32 %0, %1, %2" : "=v"(r) : "v"(a), "v"(b));
  return r;  // lo16 = bf16(a), hi16 = bf16(b)
}

// ---------------------------------------------------------------------------
// prep_x: x -> bf16 (vectorized), jmflt[b][j] = masked ? -64 : 1e30
// ---------------------------------------------------------------------------
__global__ __launch_bounds__(256) void prep_x(
    const float* __restrict__ x, const int* __restrict__ mnp, const int* __restrict__ mbert,
    unsigned short* __restrict__ xb, float* __restrict__ jmflt) {
  int tid = blockIdx.x * 256 + threadIdx.x;
  if (tid < 524288) {
    float4 v = *(const float4*)(x + tid * 4);
    ushort4 o;
    o.x = f2bf(v.x); o.y = f2bf(v.y); o.z = f2bf(v.z); o.w = f2bf(v.w);
    *(ushort4*)(xb + tid * 4) = o;
  } else {
    int o = tid - 524288;
    if (o < 4096) jmflt[o] = (mnp[o] == 0 || mbert[o] == 1) ? -64.0f : 1e30f;
  }
}

// ---------------------------------------------------------------------------
// transpose_w: LDS-tiled 64x64 transpose, coalesced read AND write.
// blocks 0..191: wqkv [512][1536] -> wqkvT [1536][512] bf16
// blocks 192..255: wout [512][512] -> whiT/wloT [512][512] bf16 hi/lo
// ---------------------------------------------------------------------------
__global__ __launch_bounds__(256) void transpose_w(
    const float* __restrict__ wqkv, const float* __restrict__ wout,
    unsigned short* __restrict__ wqkvT, unsigned short* __restrict__ whiT,
    unsigned short* __restrict__ wloT) {
  __shared__ float tile[64][65];
  int bid = blockIdx.x;
  const float* src;
  int N, k0, n0, which;
  if (bid < 192) { which = 0; src = wqkv; N = 1536; k0 = (bid / 24) * 64; n0 = (bid % 24) * 64; }
  else { bid -= 192; which = 1; src = wout; N = 512; k0 = (bid / 8) * 64; n0 = (bid % 8) * 64; }
  int tx = threadIdx.x & 63, ty = threadIdx.x >> 6;
#pragma unroll
  for (int i = 0; i < 16; ++i) {
    int row = ty + i * 4;
    tile[row][tx] = src[(k0 + row) * N + n0 + tx];
  }
  __syncthreads();
#pragma unroll
  for (int i = 0; i < 16; ++i) {
    int row = ty + i * 4;                       // n-index within tile
    float w = tile[tx][row];                    // = src[k0+tx][n0+row]
    if (which == 0) {
      wqkvT[(n0 + row) * 512 + k0 + tx] = f2bf(w);
    } else {
      unsigned short hi = f2bf(w);
      whiT[(n0 + row) * 512 + k0 + tx] = hi;
      wloT[(n0 + row) * 512 + k0 + tx] = f2bf(w - bf2f(hi));
    }
  }
}

// ---------------------------------------------------------------------------
// qkv_gemm: C[4096][1536] = xb @ Wqkv (Bt = [n][k]). 64x128 tile, 4 waves.
// Epilogue scatters q (x0.125), k ([b,h,n,d]), vT ([b,h,d,n]) bf16.
// ---------------------------------------------------------------------------
__global__ __launch_bounds__(256) void qkv_gemm(
    const unsigned short* __restrict__ A, const unsigned short* __restrict__ Bt,
    unsigned short* __restrict__ qb, unsigned short* __restrict__ kb,
    unsigned short* __restrict__ vtb) {
  __shared__ __attribute__((aligned(16))) unsigned short lA[64 * 64];
  __shared__ __attribute__((aligned(16))) unsigned short lB[128 * 64];
  const int lane = threadIdx.x & 63, wid = threadIdx.x >> 6;
  const int l15 = lane & 15, lg = lane >> 4;
  const int row0 = blockIdx.x * 64;
  const int col0 = blockIdx.y * 128;
  const int srow = lane >> 3;
  const int gslot = (lane & 7) ^ srow;
  f32x4 acc[4][2] = {};

  for (int ks = 0; ks < 8; ++ks) {
    const int k0 = ks * 64;
    __syncthreads();
#pragma unroll
    for (int i = 0; i < 2; ++i) {
      int c = wid * 2 + i;
      GLDS16(A + (row0 + c * 8 + srow) * 512 + k0 + gslot * 8, lA + c * 512);
    }
#pragma unroll
    for (int i = 0; i < 4; ++i) {
      int c = wid * 4 + i;
      GLDS16(Bt + (col0 + c * 8 + srow) * 512 + k0 + gslot * 8, lB + c * 512);
    }
    __syncthreads();
#pragma unroll
    for (int ksub = 0; ksub < 2; ++ksub) {
      short8 af[4], bfr[2];
#pragma unroll
      for (int m = 0; m < 4; ++m) {
        int row = m * 16 + l15;
        int slot = (ksub * 4 + lg) ^ (row & 7);
        af[m] = *(const short8*)(lA + row * 64 + slot * 8);
      }
#pragma unroll
      for (int n = 0; n < 2; ++n) {
        int row = wid * 32 + n * 16 + l15;
        int slot = (ksub * 4 + lg) ^ (row & 7);
        bfr[n] = *(const short8*)(lB + row * 64 + slot * 8);
      }
#pragma unroll
      for (int m = 0; m < 4; ++m)
#pragma unroll
        for (int n = 0; n < 2; ++n)
          acc[m][n] = __builtin_amdgcn_mfma_f32_16x16x32_bf16(af[m], bfr[n], acc[m][n], 0, 0, 0);
    }
  }
#pragma unroll
  for (int m = 0; m < 4; ++m) {
#pragma unroll
    for (int n = 0; n < 2; ++n) {
      int col = col0 + wid * 32 + n * 16 + l15;
      int which = col >> 9, hh = (col >> 6) & 7, d = col & 63;
#pragma unroll
      for (int r = 0; r < 4; ++r) {
        int grow = row0 + m * 16 + lg * 4 + r;
        int b = grow >> 11, np = grow & 2047;
        float v = acc[m][n][r];
        if (which == 0)
          qb[((b * 8 + hh) * 2048 + np) * 64 + d] = f2bf(v * 0.125f);  // exact pow2 scale
        else if (which == 1)
          kb[((b * 8 + hh) * 2048 + np) * 64 + d] = f2bf(v);
        else
          vtb[((b * 8 + hh) * 64 + d) * 2048 + np] = f2bf(v);
      }
    }
  }
}

// ---------------------------------------------------------------------------
// attn_kernel: fixed-max flash attention, j-split x2.
// Grid (16 bh, 32 q-blocks of 64, 2 j-splits), 4 waves; wave owns 16 q-rows.
// Swapped QK^T (A=K, B=Q): lane holds q=l15, j=16t+4lg+r. Fixed max 0,
// masked logits -> -64 via min3. Per-lane psum, one reduce at end.
// Writes f32 partial accO + lsum (combined by combine_kernel).
// ---------------------------------------------------------------------------
__global__ __launch_bounds__(256) void attn_kernel(
    const unsigned short* __restrict__ qg, const unsigned short* __restrict__ kg,
    const unsigned short* __restrict__ vtg, const int* __restrict__ mnp,
    const float* __restrict__ jmflt,
    float* __restrict__ pacc, float* __restrict__ plsum) {
  __shared__ __attribute__((aligned(16))) unsigned short Plds[4][16 * 72];
  const int lane = threadIdx.x & 63, wid = threadIdx.x >> 6;
  const int l15 = lane & 15, lg = lane >> 4;
  const int bh = blockIdx.x, b = bh >> 3;
  const int q0 = blockIdx.y * 64 + wid * 16;
  const int js = blockIdx.z;
  const unsigned short* Q = qg + bh * (2048 * 64);
  const unsigned short* K = kg + bh * (2048 * 64);
  const unsigned short* VT = vtg + bh * (64 * 2048);

  short8 qf[2];
#pragma unroll
  for (int s = 0; s < 2; ++s)
    qf[s] = *(const short8*)(Q + (q0 + l15) * 64 + s * 32 + lg * 8);
  const float rowflt = (mnp[b * 2048 + q0 + l15] == 0) ? -64.0f : 1e30f;

  f32x4 accO[4] = {};
  float psum = 0.0f;
  unsigned short* Pl = &Plds[wid][0];

  for (int jt = 0; jt < 16; ++jt) {
    const int j0 = js * 1024 + jt * 64;
    short8 kf[4][2];
    f32x4 jm[4];
#pragma unroll
    for (int t = 0; t < 4; ++t) {
      jm[t] = *(const f32x4*)(jmflt + b * 2048 + j0 + t * 16 + lg * 4);
#pragma unroll
      for (int s = 0; s < 2; ++s)
        kf[t][s] = *(const short8*)(K + (j0 + t * 16 + l15) * 64 + s * 32 + lg * 8);
    }
    short8 vf[4][2];
#pragma unroll
    for (int dt = 0; dt < 4; ++dt)
#pragma unroll
      for (int c = 0; c < 2; ++c)
        vf[dt][c] = *(const short8*)(VT + (dt * 16 + l15) * 2048 + j0 + c * 32 + lg * 8);

    f32x4 sacc[4] = {};
#pragma unroll
    for (int t = 0; t < 4; ++t)
#pragma unroll
      for (int s = 0; s < 2; ++s)
        sacc[t] = __builtin_amdgcn_mfma_f32_16x16x32_bf16(kf[t][s], qf[s], sacc[t], 0, 0, 0);

#pragma unroll
    for (int t = 0; t < 4; ++t) {
      float e[4];
#pragma unroll
      for (int r = 0; r < 4; ++r) {
        float sv = fminf(fminf(sacc[t][r], jm[t][r]), rowflt);  // v_min3
        e[r] = __expf(sv);
        psum += e[r];
      }
      unsigned p01 = cvt_pk_bf16(e[0], e[1]);
      unsigned p23 = cvt_pk_bf16(e[2], e[3]);
      *(unsigned*)(Pl + l15 * 72 + t * 16 + lg * 4 + 0) = p01;
      *(unsigned*)(Pl + l15 * 72 + t * 16 + lg * 4 + 2) = p23;
    }
    short8 pa[2];
#pragma unroll
    for (int c = 0; c < 2; ++c)
      pa[c] = *(const short8*)(Pl + l15 * 72 + c * 32 + lg * 8);
#pragma unroll
    for (int dt = 0; dt < 4; ++dt)
#pragma unroll
      for (int c = 0; c < 2; ++c)
        accO[dt] = __builtin_amdgcn_mfma_f32_16x16x32_bf16(pa[c], vf[dt][c], accO[dt], 0, 0, 0);
  }
  // row-sum lives distributed over lane groups: reduce across lg
  psum += __shfl_xor(psum, 16);
  psum += __shfl_xor(psum, 32);

  float* PA = pacc + (size_t)(js * 16 + bh) * 2048 * 64;
#pragma unroll
  for (int dt = 0; dt < 4; ++dt)
#pragma unroll
    for (int r = 0; r < 4; ++r)
      PA[(q0 + lg * 4 + r) * 64 + dt * 16 + l15] = accO[dt][r];
  if (lane < 16) plsum[(js * 16 + bh) * 2048 + q0 + lane] = psum;
}

// ---------------------------------------------------------------------------
// combine_kernel: sum the 2 j-split partials, normalize, hi/lo bf16 split.
// ---------------------------------------------------------------------------
__global__ __launch_bounds__(256) void combine_kernel(
    const float* __restrict__ pacc, const float* __restrict__ plsum,
    unsigned short* __restrict__ ahi, unsigned short* __restrict__ alo) {
  int tid = blockIdx.x * 256 + threadIdx.x;  // 0..2M-1
  int row = tid >> 9, col = tid & 511;
  int b = row >> 11, n = row & 2047;
  int h = col >> 6, d = col & 63;
  int bh = b * 8 + h;
  float a = 0.f, l = 0.f;
#pragma unroll
  for (int js = 0; js < 2; ++js) {
    a += pacc[((size_t)(js * 16 + bh) * 2048 + n) * 64 + d];
    l += plsum[(js * 16 + bh) * 2048 + n];
  }
  float val = a / l;
  unsigned short hi = f2bf(val);
  ahi[tid] = hi;
  alo[tid] = f2bf(val - bf2f(hi));
}

// ---------------------------------------------------------------------------
// outproj_gemm: split-bf16 GEMM, virtual K=1536 (AhiWhi + AloWhi + AhiWlo).
// 32x128 tile, 4 waves (each 32x32), grid (128,4) = 512 blocks.
// ---------------------------------------------------------------------------
__global__ __launch_bounds__(256) void outproj_gemm(
    const unsigned short* __restrict__ Ahi, const unsigned short* __restrict__ Alo,
    const unsigned short* __restrict__ WhiT, const unsigned short* __restrict__ WloT,
    const float* __restrict__ bias, float* __restrict__ out) {
  __shared__ __attribute__((aligned(16))) unsigned short lA[32 * 64];
  __shared__ __attribute__((aligned(16))) unsigned short lB[128 * 64];
  const int lane = threadIdx.x & 63, wid = threadIdx.x >> 6;
  const int l15 = lane & 15, lg = lane >> 4;
  const int row0 = blockIdx.x * 32;
  const int col0 = blockIdx.y * 128;
  const int srow = lane >> 3;
  const int gslot = (lane & 7) ^ srow;
  f32x4 acc[2][2] = {};

  for (int ks = 0; ks < 24; ++ks) {
    const int seg = ks >> 3;
    const int k0 = (ks & 7) * 64;
    const unsigned short* Asrc = (seg == 1) ? Alo : Ahi;
    const unsigned short* Bsrc = (seg == 2) ? WloT : WhiT;
    __syncthreads();
    GLDS16(Asrc + (row0 + wid * 8 + srow) * 512 + k0 + gslot * 8, lA + wid * 512);
#pragma unroll
    for (int i = 0; i < 4; ++i) {
      int c = wid * 4 + i;
      GLDS16(Bsrc + (col0 + c * 8 + srow) * 512 + k0 + gslot * 8, lB + c * 512);
    }
    __syncthreads();
#pragma unroll
    for (int ksub = 0; ksub < 2; ++ksub) {
      short8 af[2], bfr[2];
#pragma unroll
      for (int m = 0; m < 2; ++m) {
        int row = m * 16 + l15;
        int slot = (ksub * 4 + lg) ^ (row & 7);
        af[m] = *(const short8*)(lA + row * 64 + slot * 8);
      }
#pragma unroll
      for (int n = 0; n < 2; ++n) {
        int row = wid * 32 + n * 16 + l15;
        int slot = (ksub * 4 + lg) ^ (row & 7);
        bfr[n] = *(const short8*)(lB + row * 64 + slot * 8);
      }
#pragma unroll
      for (int m = 0; m < 2; ++m)
#pragma unroll
        for (int n = 0; n < 2; ++n)
          acc[m][n] = __builtin_amdgcn_mfma_f32_16x16x32_bf16(af[m], bfr[n], acc[m][n], 0, 0, 0);
    }
  }
#pragma unroll
  for (int m = 0; m < 2; ++m) {
#pragma unroll
    for (int n = 0; n < 2; ++n) {
      int col = col0 + wid * 32 + n * 16 + l15;
      float bb = bias[col];
#pragma unroll
      for (int r = 0; r < 4; ++r) {
        int grow = row0 + m * 16 + lg * 4 + r;
        out[grow * 512 + col] = acc[m][n][r] + bb;
      }
    }
  }
}

// ---------------------------------------------------------------------------
extern "C" void kernel_launch(void* const* d_in, const int* in_sizes, int n_in,
                              void* d_out, int out_size, void* d_ws, size_t ws_size,
                              hipStream_t stream) {
  (void)in_sizes; (void)n_in; (void)out_size; (void)ws_size;
  const float* x = (const float*)d_in[0];
  const int* mnp = (const int*)d_in[1];
  const int* mbert = (const int*)d_in[2];
  const float* wqkv = (const float*)d_in[3];
  const float* wout = (const float*)d_in[4];
  const float* bout = (const float*)d_in[5];
  float* out = (float*)d_out;

  char* ws = (char*)d_ws;
  size_t off = 0;
  auto alloc = [&](size_t bytes) {
    void* p = ws + off;
    off += (bytes + 255) & ~(size_t)255;
    return p;
  };
  unsigned short* xb    = (unsigned short*)alloc(2097152 * 2);   // x bf16 [4096][512]
  unsigned short* wqkvT = (unsigned short*)alloc(786432 * 2);    // [1536][512]
  unsigned short* qb    = (unsigned short*)alloc(2097152 * 2);   // [b,h,n,d] (x0.125)
  unsigned short* kb    = (unsigned short*)alloc(2097152 * 2);   // [b,h,n,d]
  unsigned short* vtb   = (unsigned short*)alloc(2097152 * 2);   // [b,h,d,n]
  unsigned short* ahi   = (unsigned short*)alloc(2097152 * 2);   // attn out hi
  unsigned short* alo   = (unsigned short*)alloc(2097152 * 2);   // attn out lo
  unsigned short* whiT  = (unsigned short*)alloc(262144 * 2);    // [512][512] n-major
  unsigned short* wloT  = (unsigned short*)alloc(262144 * 2);
  float* jmflt          = (float*)alloc(4096 * 4);
  float* pacc           = (float*)alloc((size_t)2 * 16 * 2048 * 64 * 4);  // 16.8 MB
  float* plsum          = (float*)alloc(2 * 16 * 2048 * 4);

  prep_x<<<2064, 256, 0, stream>>>(x, mnp, mbert, xb, jmflt);
  transpose_w<<<256, 256, 0, stream>>>(wqkv, wout, wqkvT, whiT, wloT);
  qkv_gemm<<<dim3(64, 12), 256, 0, stream>>>(xb, wqkvT, qb, kb, vtb);
  attn_kernel<<<dim3(16, 32, 2), 256, 0, stream>>>(qb, kb, vtb, mnp, jmflt, pacc, plsum);
  combine_kernel<<<8192, 256, 0, stream>>>(pacc, plsum, ahi, alo);
  outproj_gemm<<<dim3(128, 4), 256, 0, stream>>>(ahi, alo, whiT, wloT, bout, out);
}

// Round 4
// 141.742 us; speedup vs baseline: 1.6515x; 1.6515x over previous
//
#include <hip/hip_runtime.h>

typedef __attribute__((ext_vector_type(8))) short short8;
typedef __attribute__((ext_vector_type(4))) float f32x4;

#define GLDS16(gp, lp)                                                                     \
  __builtin_amdgcn_global_load_lds(                                                        \
      (const __attribute__((address_space(1))) unsigned int*)(gp),                         \
      (__attribute__((address_space(3))) unsigned int*)(lp), 16, 0, 0)

__device__ __forceinline__ unsigned short f2bf(float f) {
  unsigned u = __float_as_uint(f);
  u += 0x7FFFu + ((u >> 16) & 1u);
  return (unsigned short)(u >> 16);
}
__device__ __forceinline__ float bf2f(unsigned short h) {
  return __uint_as_float(((unsigned)h) << 16);
}
__device__ __forceinline__ unsigned cvt_pk_bf16(float a, float b) {
  unsigned r;
  asm("v_cvt_pk_bf16_f32 %0, %1, %2" : "=v"(r) : "v"(a), "v"(b));
  return r;  // lo16 = bf16(a), hi16 = bf16(b)
}

// ---------------------------------------------------------------------------
// prep_x: x -> bf16 (vectorized), jmflt[b][j] = masked ? -64 : 1e30
// ---------------------------------------------------------------------------
__global__ __launch_bounds__(256) void prep_x(
    const float* __restrict__ x, const int* __restrict__ mnp, const int* __restrict__ mbert,
    unsigned short* __restrict__ xb, float* __restrict__ jmflt) {
  int tid = blockIdx.x * 256 + threadIdx.x;
  if (tid < 524288) {
    float4 v = *(const float4*)(x + tid * 4);
    ushort4 o;
    o.x = f2bf(v.x); o.y = f2bf(v.y); o.z = f2bf(v.z); o.w = f2bf(v.w);
    *(ushort4*)(xb + tid * 4) = o;
  } else {
    int o = tid - 524288;
    if (o < 4096) jmflt[o] = (mnp[o] == 0 || mbert[o] == 1) ? -64.0f : 1e30f;
  }
}

// ---------------------------------------------------------------------------
// transpose_w: LDS-tiled 64x64 transpose, coalesced read AND write.
// blocks 0..191: wqkv [512][1536] -> wqkvT [1536][512] bf16
// blocks 192..255: wout [512][512] -> whiT/wloT [512][512] bf16 hi/lo
// ---------------------------------------------------------------------------
__global__ __launch_bounds__(256) void transpose_w(
    const float* __restrict__ wqkv, const float* __restrict__ wout,
    unsigned short* __restrict__ wqkvT, unsigned short* __restrict__ whiT,
    unsigned short* __restrict__ wloT) {
  __shared__ float tile[64][65];
  int bid = blockIdx.x;
  const float* src;
  int N, k0, n0, which;
  if (bid < 192) { which = 0; src = wqkv; N = 1536; k0 = (bid / 24) * 64; n0 = (bid % 24) * 64; }
  else { bid -= 192; which = 1; src = wout; N = 512; k0 = (bid / 8) * 64; n0 = (bid % 8) * 64; }
  int tx = threadIdx.x & 63, ty = threadIdx.x >> 6;
#pragma unroll
  for (int i = 0; i < 16; ++i) {
    int row = ty + i * 4;
    tile[row][tx] = src[(k0 + row) * N + n0 + tx];
  }
  __syncthreads();
#pragma unroll
  for (int i = 0; i < 16; ++i) {
    int row = ty + i * 4;                       // n-index within tile
    float w = tile[tx][row];                    // = src[k0+tx][n0+row]
    if (which == 0) {
      wqkvT[(n0 + row) * 512 + k0 + tx] = f2bf(w);
    } else {
      unsigned short hi = f2bf(w);
      whiT[(n0 + row) * 512 + k0 + tx] = hi;
      wloT[(n0 + row) * 512 + k0 + tx] = f2bf(w - bf2f(hi));
    }
  }
}

// ---------------------------------------------------------------------------
// qkv_gemm: C[4096][1536] = xb @ Wqkv (Bt = [n][k]). 64x128 tile, 4 waves.
// Epilogue scatters q (x0.125), k ([b,h,n,d]), vT ([b,h,d,n]) bf16.
// ---------------------------------------------------------------------------
__global__ __launch_bounds__(256) void qkv_gemm(
    const unsigned short* __restrict__ A, const unsigned short* __restrict__ Bt,
    unsigned short* __restrict__ qb, unsigned short* __restrict__ kb,
    unsigned short* __restrict__ vtb) {
  __shared__ __attribute__((aligned(16))) unsigned short lA[64 * 64];
  __shared__ __attribute__((aligned(16))) unsigned short lB[128 * 64];
  const int lane = threadIdx.x & 63, wid = threadIdx.x >> 6;
  const int l15 = lane & 15, lg = lane >> 4;
  const int row0 = blockIdx.x * 64;
  const int col0 = blockIdx.y * 128;
  const int srow = lane >> 3;
  const int gslot = (lane & 7) ^ srow;
  f32x4 acc[4][2] = {};

  for (int ks = 0; ks < 8; ++ks) {
    const int k0 = ks * 64;
    __syncthreads();
#pragma unroll
    for (int i = 0; i < 2; ++i) {
      int c = wid * 2 + i;
      GLDS16(A + (row0 + c * 8 + srow) * 512 + k0 + gslot * 8, lA + c * 512);
    }
#pragma unroll
    for (int i = 0; i < 4; ++i) {
      int c = wid * 4 + i;
      GLDS16(Bt + (col0 + c * 8 + srow) * 512 + k0 + gslot * 8, lB + c * 512);
    }
    __syncthreads();
#pragma unroll
    for (int ksub = 0; ksub < 2; ++ksub) {
      short8 af[4], bfr[2];
#pragma unroll
      for (int m = 0; m < 4; ++m) {
        int row = m * 16 + l15;
        int slot = (ksub * 4 + lg) ^ (row & 7);
        af[m] = *(const short8*)(lA + row * 64 + slot * 8);
      }
#pragma unroll
      for (int n = 0; n < 2; ++n) {
        int row = wid * 32 + n * 16 + l15;
        int slot = (ksub * 4 + lg) ^ (row & 7);
        bfr[n] = *(const short8*)(lB + row * 64 + slot * 8);
      }
#pragma unroll
      for (int m = 0; m < 4; ++m)
#pragma unroll
        for (int n = 0; n < 2; ++n)
          acc[m][n] = __builtin_amdgcn_mfma_f32_16x16x32_bf16(af[m], bfr[n], acc[m][n], 0, 0, 0);
    }
  }
#pragma unroll
  for (int m = 0; m < 4; ++m) {
#pragma unroll
    for (int n = 0; n < 2; ++n) {
      int col = col0 + wid * 32 + n * 16 + l15;
      int which = col >> 9, hh = (col >> 6) & 7, d = col & 63;
#pragma unroll
      for (int r = 0; r < 4; ++r) {
        int grow = row0 + m * 16 + lg * 4 + r;
        int b = grow >> 11, np = grow & 2047;
        float v = acc[m][n][r];
        if (which == 0)
          qb[((b * 8 + hh) * 2048 + np) * 64 + d] = f2bf(v * 0.125f);  // exact pow2 scale
        else if (which == 1)
          kb[((b * 8 + hh) * 2048 + np) * 64 + d] = f2bf(v);
        else
          vtb[((b * 8 + hh) * 64 + d) * 2048 + np] = f2bf(v);
      }
    }
  }
}

// ---------------------------------------------------------------------------
// attn_kernel v3: LDS-staged double-buffered flash attention, fixed-max.
// Grid (16 bh, 32 q-blocks of 64), 4 waves; wave owns 16 q-rows; 32 j-tiles.
// Per iter: K-tile (8KB) + V-tile (8KB) staged ONCE per block via
// global_load_lds (pre-swizzled source), counted vmcnt(4) + raw s_barrier
// keeps next tile's loads in flight across the barrier (2-phase pipeline).
// jmask staged to LDS in prologue so per-iter VMEM = exactly 4 stage loads.
// Writes final ahi/alo directly (no j-split, no combine pass).
// ---------------------------------------------------------------------------
__global__ __launch_bounds__(256) void attn_kernel(
    const unsigned short* __restrict__ qg, const unsigned short* __restrict__ kg,
    const unsigned short* __restrict__ vtg, const int* __restrict__ mnp,
    const float* __restrict__ jmflt,
    unsigned short* __restrict__ ahi, unsigned short* __restrict__ alo) {
  __shared__ __attribute__((aligned(16))) unsigned short Kbuf[2][64 * 64];  // [j][d] swz
  __shared__ __attribute__((aligned(16))) unsigned short Vbuf[2][64 * 64];  // [d][j] swz
  __shared__ __attribute__((aligned(16))) float jmlds[2048];
  __shared__ __attribute__((aligned(16))) unsigned short Plds[4][16 * 72];
  const int lane = threadIdx.x & 63, wid = threadIdx.x >> 6;
  const int l15 = lane & 15, lg = lane >> 4;
  const int srow = lane >> 3, gslot = (lane & 7) ^ srow;
  const int bh = blockIdx.x, b = bh >> 3, h = bh & 7;
  const int q0 = blockIdx.y * 64 + wid * 16;
  const unsigned short* Q = qg + bh * (2048 * 64);
  const unsigned short* K = kg + bh * (2048 * 64);
  const unsigned short* VT = vtg + bh * (64 * 2048);

  // ---- prologue staging: jmask (8KB, 2 instr/wave) + tile 0 (4 instr/wave)
#pragma unroll
  for (int i = 0; i < 2; ++i)
    GLDS16(jmflt + b * 2048 + wid * 512 + i * 256 + lane * 4, jmlds + wid * 512 + i * 256);
#pragma unroll
  for (int i = 0; i < 2; ++i)
    GLDS16(K + (wid * 16 + i * 8 + srow) * 64 + gslot * 8, &Kbuf[0][(wid * 16 + i * 8) * 64]);
#pragma unroll
  for (int i = 0; i < 2; ++i)
    GLDS16(VT + (wid * 16 + i * 8 + srow) * 2048 + gslot * 8, &Vbuf[0][(wid * 16 + i * 8) * 64]);

  short8 qf[2];
#pragma unroll
  for (int s = 0; s < 2; ++s)
    qf[s] = *(const short8*)(Q + (q0 + l15) * 64 + s * 32 + lg * 8);
  const float rowflt = (mnp[b * 2048 + q0 + l15] == 0) ? -64.0f : 1e30f;

  f32x4 accO[4] = {};
  float psum = 0.0f;
  unsigned short* Pl = &Plds[wid][0];
  int cur = 0;

  for (int jt = 0; jt < 32; ++jt) {
    const int j0 = jt * 64;
    if (jt < 31) {
      const int jn = j0 + 64;
      const int nb = cur ^ 1;
#pragma unroll
      for (int i = 0; i < 2; ++i)
        GLDS16(K + (jn + wid * 16 + i * 8 + srow) * 64 + gslot * 8,
               &Kbuf[nb][(wid * 16 + i * 8) * 64]);
#pragma unroll
      for (int i = 0; i < 2; ++i)
        GLDS16(VT + (wid * 16 + i * 8 + srow) * 2048 + jn + gslot * 8,
               &Vbuf[nb][(wid * 16 + i * 8) * 64]);
      asm volatile("s_waitcnt vmcnt(4)" ::: "memory");  // current tile landed; next in flight
    } else {
      asm volatile("s_waitcnt vmcnt(0)" ::: "memory");
    }
    __builtin_amdgcn_s_barrier();

    // fragment reads from LDS (swizzled: elem ^ (row&7)*8 -> ~2-way, free)
    short8 kf[4][2], vf[4][2];
    f32x4 jm[4];
    const int sw = (l15 & 7) * 8;
#pragma unroll
    for (int t = 0; t < 4; ++t) {
      const int row = t * 16 + l15;
#pragma unroll
      for (int s = 0; s < 2; ++s)
        kf[t][s] = *(const short8*)(&Kbuf[cur][row * 64 + ((s * 32 + lg * 8) ^ sw)]);
      jm[t] = *(const f32x4*)(&jmlds[j0 + t * 16 + lg * 4]);
    }
#pragma unroll
    for (int dt = 0; dt < 4; ++dt) {
      const int row = dt * 16 + l15;
#pragma unroll
      for (int c = 0; c < 2; ++c)
        vf[dt][c] = *(const short8*)(&Vbuf[cur][row * 64 + ((c * 32 + lg * 8) ^ sw)]);
    }

    f32x4 sacc[4] = {};
#pragma unroll
    for (int t = 0; t < 4; ++t)
#pragma unroll
      for (int s = 0; s < 2; ++s)
        sacc[t] = __builtin_amdgcn_mfma_f32_16x16x32_bf16(kf[t][s], qf[s], sacc[t], 0, 0, 0);

#pragma unroll
    for (int t = 0; t < 4; ++t) {
      float e[4];
#pragma unroll
      for (int r = 0; r < 4; ++r) {
        float sv = fminf(fminf(sacc[t][r], jm[t][r]), rowflt);  // v_min3
        e[r] = __expf(sv);
        psum += e[r];
      }
      unsigned p01 = cvt_pk_bf16(e[0], e[1]);
      unsigned p23 = cvt_pk_bf16(e[2], e[3]);
      *(unsigned*)(Pl + l15 * 72 + t * 16 + lg * 4 + 0) = p01;
      *(unsigned*)(Pl + l15 * 72 + t * 16 + lg * 4 + 2) = p23;
    }
    short8 pa[2];
#pragma unroll
    for (int c = 0; c < 2; ++c)
      pa[c] = *(const short8*)(Pl + l15 * 72 + c * 32 + lg * 8);
#pragma unroll
    for (int dt = 0; dt < 4; ++dt)
#pragma unroll
      for (int c = 0; c < 2; ++c)
        accO[dt] = __builtin_amdgcn_mfma_f32_16x16x32_bf16(pa[c], vf[dt][c], accO[dt], 0, 0, 0);

    __builtin_amdgcn_s_barrier();  // all waves done reading tile jt before its buf is restaged
    cur ^= 1;
  }

  // ---- epilogue: row-sum reduce, normalize, hi/lo bf16 split, direct store
  psum += __shfl_xor(psum, 16);
  psum += __shfl_xor(psum, 32);   // every lane now holds rowsum for q-local = its l15
  float lsum[4];
#pragma unroll
  for (int r = 0; r < 4; ++r) lsum[r] = __shfl(psum, lg * 4 + r);
#pragma unroll
  for (int dt = 0; dt < 4; ++dt) {
#pragma unroll
    for (int r = 0; r < 4; ++r) {
      float val = accO[dt][r] / lsum[r];
      int row = q0 + lg * 4 + r;
      int col = h * 64 + dt * 16 + l15;
      unsigned short hi = f2bf(val);
      ahi[(b * 2048 + row) * 512 + col] = hi;
      alo[(b * 2048 + row) * 512 + col] = f2bf(val - bf2f(hi));
    }
  }
}

// ---------------------------------------------------------------------------
// outproj_gemm: split-bf16 GEMM, virtual K=1536 (AhiWhi + AloWhi + AhiWlo).
// 32x128 tile, 4 waves (each 32x32), grid (128,4) = 512 blocks.
// ---------------------------------------------------------------------------
__global__ __launch_bounds__(256) void outproj_gemm(
    const unsigned short* __restrict__ Ahi, const unsigned short* __restrict__ Alo,
    const unsigned short* __restrict__ WhiT, const unsigned short* __restrict__ WloT,
    const float* __restrict__ bias, float* __restrict__ out) {
  __shared__ __attribute__((aligned(16))) unsigned short lA[32 * 64];
  __shared__ __attribute__((aligned(16))) unsigned short lB[128 * 64];
  const int lane = threadIdx.x & 63, wid = threadIdx.x >> 6;
  const int l15 = lane & 15, lg = lane >> 4;
  const int row0 = blockIdx.x * 32;
  const int col0 = blockIdx.y * 128;
  const int srow = lane >> 3;
  const int gslot = (lane & 7) ^ srow;
  f32x4 acc[2][2] = {};

  for (int ks = 0; ks < 24; ++ks) {
    const int seg = ks >> 3;
    const int k0 = (ks & 7) * 64;
    const unsigned short* Asrc = (seg == 1) ? Alo : Ahi;
    const unsigned short* Bsrc = (seg == 2) ? WloT : WhiT;
    __syncthreads();
    GLDS16(Asrc + (row0 + wid * 8 + srow) * 512 + k0 + gslot * 8, lA + wid * 512);
#pragma unroll
    for (int i = 0; i < 4; ++i) {
      int c = wid * 4 + i;
      GLDS16(Bsrc + (col0 + c * 8 + srow) * 512 + k0 + gslot * 8, lB + c * 512);
    }
    __syncthreads();
#pragma unroll
    for (int ksub = 0; ksub < 2; ++ksub) {
      short8 af[2], bfr[2];
#pragma unroll
      for (int m = 0; m < 2; ++m) {
        int row = m * 16 + l15;
        int slot = (ksub * 4 + lg) ^ (row & 7);
        af[m] = *(const short8*)(lA + row * 64 + slot * 8);
      }
#pragma unroll
      for (int n = 0; n < 2; ++n) {
        int row = wid * 32 + n * 16 + l15;
        int slot = (ksub * 4 + lg) ^ (row & 7);
        bfr[n] = *(const short8*)(lB + row * 64 + slot * 8);
      }
#pragma unroll
      for (int m = 0; m < 2; ++m)
#pragma unroll
        for (int n = 0; n < 2; ++n)
          acc[m][n] = __builtin_amdgcn_mfma_f32_16x16x32_bf16(af[m], bfr[n], acc[m][n], 0, 0, 0);
    }
  }
#pragma unroll
  for (int m = 0; m < 2; ++m) {
#pragma unroll
    for (int n = 0; n < 2; ++n) {
      int col = col0 + wid * 32 + n * 16 + l15;
      float bb = bias[col];
#pragma unroll
      for (int r = 0; r < 4; ++r) {
        int grow = row0 + m * 16 + lg * 4 + r;
        out[grow * 512 + col] = acc[m][n][r] + bb;
      }
    }
  }
}

// ---------------------------------------------------------------------------
extern "C" void kernel_launch(void* const* d_in, const int* in_sizes, int n_in,
                              void* d_out, int out_size, void* d_ws, size_t ws_size,
                              hipStream_t stream) {
  (void)in_sizes; (void)n_in; (void)out_size; (void)ws_size;
  const float* x = (const float*)d_in[0];
  const int* mnp = (const int*)d_in[1];
  const int* mbert = (const int*)d_in[2];
  const float* wqkv = (const float*)d_in[3];
  const float* wout = (const float*)d_in[4];
  const float* bout = (const float*)d_in[5];
  float* out = (float*)d_out;

  char* ws = (char*)d_ws;
  size_t off = 0;
  auto alloc = [&](size_t bytes) {
    void* p = ws + off;
    off += (bytes + 255) & ~(size_t)255;
    return p;
  };
  unsigned short* xb    = (unsigned short*)alloc(2097152 * 2);   // x bf16 [4096][512]
  unsigned short* wqkvT = (unsigned short*)alloc(786432 * 2);    // [1536][512]
  unsigned short* qb    = (unsigned short*)alloc(2097152 * 2);   // [b,h,n,d] (x0.125)
  unsigned short* kb    = (unsigned short*)alloc(2097152 * 2);   // [b,h,n,d]
  unsigned short* vtb   = (unsigned short*)alloc(2097152 * 2);   // [b,h,d,n]
  unsigned short* ahi   = (unsigned short*)alloc(2097152 * 2);   // attn out hi
  unsigned short* alo   = (unsigned short*)alloc(2097152 * 2);   // attn out lo
  unsigned short* whiT  = (unsigned short*)alloc(262144 * 2);    // [512][512] n-major
  unsigned short* wloT  = (unsigned short*)alloc(262144 * 2);
  float* jmflt          = (float*)alloc(4096 * 4);

  prep_x<<<2064, 256, 0, stream>>>(x, mnp, mbert, xb, jmflt);
  transpose_w<<<256, 256, 0, stream>>>(wqkv, wout, wqkvT, whiT, wloT);
  qkv_gemm<<<dim3(64, 12), 256, 0, stream>>>(xb, wqkvT, qb, kb, vtb);
  attn_kernel<<<dim3(16, 32), 256, 0, stream>>>(qb, kb, vtb, mnp, jmflt, ahi, alo);
  outproj_gemm<<<dim3(128, 4), 256, 0, stream>>>(ahi, alo, whiT, wloT, bout, out);
}